// Round 14
// baseline (288.573 us; speedup 1.0000x reference)
//
#include <hip/hip_runtime.h>
#include <stdint.h>
#include <math.h>

// RPN proposal filtering: decode -> clip -> validity mask -> stable top-2000
// -> greedy NMS (IoU > 0.7) -> first 1000 kept -> (B, 1000, 5).
//
// R20: k_nmsmask residency-forcing experiment. Four structures converged at
// ~56us (R15 1-wave blocks, R16 4-wave, R18 unroll 73us, R19 4-row/wave):
// VALU issue floor is ~12-16us, so we sit 3.5x above it with VALUBusy ~50%
// and occupancy PINNED ~8.6 waves/CU whenever more were available. The one
// untested variable: forcing co-residency. 1024-thread (16-wave) blocks make
// the HW hold 16 waves per workgroup; 3 blocks/CU available -> 32 waves/CU
// requested. Body is R16's PROVEN loop unchanged (single-variable test).
// Wave w covers col-tile jb = qc*16 + w; grid (2, NW, B).

#define IMGF 1024.0f
#define PRE_NMS 2000
#define POST_NMS 1000
#define NMS_THR 0.7f
#define MIN_SZ 16.0f
#define CAP 4096          // candidate buffer per batch
#define SEL 2048          // padded selection stride (>= PRE_NMS)
#define NW (SEL / 64)     // 32 mask words per row
#define CNT_STRIDE 32     // u32s per batch for counters (128 B -> own line)
#define KEY_NEGINF 0x007FFFFFu  // f2key(-inf)
#define MAXCHUNK 12

// Order-preserving float -> u32 key (all floats incl. -inf totally ordered).
__device__ __forceinline__ uint32_t f2key(float f) {
  uint32_t u = __float_as_uint(f);
  return (u & 0x80000000u) ? ~u : (u | 0x80000000u);
}
__device__ __forceinline__ float key2f(uint32_t k) {
  uint32_t u = (k & 0x80000000u) ? (k & 0x7FFFFFFFu) : ~k;
  return __uint_as_float(u);
}

__device__ __forceinline__ unsigned long long readlane_u64(unsigned long long v,
                                                           int lane) {
  unsigned int lo = __builtin_amdgcn_readlane((unsigned int)v, lane);
  unsigned int hi = __builtin_amdgcn_readlane((unsigned int)(v >> 32), lane);
  return ((unsigned long long)hi << 32) | lo;
}

// Mirrors reference _decode + clip, fp32.
__device__ __forceinline__ float4 decode_clip(float4 anc, float4 dlt) {
  float aw = anc.z - anc.x;
  float ah = anc.w - anc.y;
  float ax = anc.x + 0.5f * aw;
  float ay = anc.y + 0.5f * ah;
  float dw = fminf(dlt.z, 4.0f);
  float dh = fminf(dlt.w, 4.0f);
  float px = dlt.x * aw + ax;
  float py = dlt.y * ah + ay;
  float pw = expf(dw) * aw;
  float ph = expf(dh) * ah;
  float x1 = px - 0.5f * pw, y1 = py - 0.5f * ph;
  float x2 = px + 0.5f * pw, y2 = py + 0.5f * ph;
  x1 = fminf(fmaxf(x1, 0.0f), IMGF);
  y1 = fminf(fmaxf(y1, 0.0f), IMGF);
  x2 = fminf(fmaxf(x2, 0.0f), IMGF);
  y2 = fminf(fmaxf(y2, 0.0f), IMGF);
  return make_float4(x1, y1, x2, y2);
}

// K1: decode -> masked-score key; per-block LDS coarse hist of key>>24
// (finite keys only), ballot-match wave aggregation, one aggregated global
// flush per block. grid = (bpb, B).
__global__ void k_decode(const float4* __restrict__ anchors,
                         const float4* __restrict__ deltas,
                         const float* __restrict__ scores,
                         uint32_t* __restrict__ keys,
                         uint32_t* __restrict__ chist,
                         int A, int chunks) {
  int b = blockIdx.y;
  int t = threadIdx.x;  // 256
  int lane = t & 63;
  __shared__ uint32_t shist[256];
  shist[t] = 0;
  __syncthreads();
  int base_a = blockIdx.x * (chunks * 256);
  for (int c = 0; c < chunks; c++) {
    int a = base_a + c * 256 + t;
    bool inb = a < A;
    int ac = inb ? a : (A - 1);
    size_t i = (size_t)b * A + ac;
    float4 box = decode_clip(anchors[ac], deltas[i]);
    bool valid = (box.z - box.x >= MIN_SZ) && (box.w - box.y >= MIN_SZ);
    float ms = valid ? scores[i] : -INFINITY;
    uint32_t k = f2key(ms);
    if (inb) keys[i] = k;
    uint32_t bucket = k >> 24;
    bool fin = inb && (k != KEY_NEGINF);
    // lanes with equal bucket -> one LDS atomic by the leader
    unsigned long long match = __ballot(fin);
#pragma unroll
    for (int bit = 0; bit < 8; bit++) {
      bool hb = (bucket >> bit) & 1;
      unsigned long long bb = __ballot(hb && fin);
      match &= hb ? bb : ~bb;
    }
    if (fin && (__ffsll((long long)match) - 1 == lane))
      atomicAdd(&shist[bucket], (uint32_t)__popcll(match));
  }
  __syncthreads();
  uint32_t v = shist[t];
  if (v) atomicAdd(&chist[b * 256 + t], v);
}

// K2: pick coarse bucket cb s.t. countAbove(cb) < PRE_NMS <= countAbove(cb)+chist[cb].
__global__ void k_coarse(const uint32_t* __restrict__ chist,
                         int* __restrict__ cbArr,
                         uint32_t* __restrict__ cumArr) {
  int b = blockIdx.x;
  int t = threadIdx.x;  // 256
  __shared__ uint32_t sA[256];
  sA[t] = chist[b * 256 + t];
  for (int d = 1; d < 256; d <<= 1) {  // inclusive suffix scan
    __syncthreads();
    uint32_t v = sA[t] + ((t + d < 256) ? sA[t + d] : 0u);
    __syncthreads();
    sA[t] = v;
  }
  __syncthreads();
  if (t == 0 && sA[0] < PRE_NMS) {  // degenerate: < PRE_NMS finite entries
    cbArr[b] = -1;
    cumArr[b] = 0;
  }
  uint32_t nxt = (t < 255) ? sA[t + 1] : 0u;
  if (sA[t] >= PRE_NMS && nxt < PRE_NMS) {
    cbArr[b] = t;
    cumArr[b] = nxt;  // count strictly above coarse bucket t
  }
}

// K3: fine hist of key bits[23:16] for elements whose coarse bucket == cb[b].
__global__ void k_fine(const uint32_t* __restrict__ keys,
                       const int* __restrict__ cbArr,
                       uint32_t* __restrict__ fhist,
                       int A, int chunks) {
  int b = blockIdx.y;
  int t = threadIdx.x;  // 256
  int cb = cbArr[b];
  if (cb < 0) return;
  __shared__ uint32_t shist[256];
  shist[t] = 0;
  __syncthreads();
  int base_a = blockIdx.x * (chunks * 256);
  uint32_t cbu = (uint32_t)cb;
  for (int c = 0; c < chunks; c++) {
    int a = base_a + c * 256 + t;
    if (a >= A) break;
    uint32_t k = keys[(size_t)b * A + a];
    if ((k >> 24) == cbu && k != KEY_NEGINF)
      atomicAdd(&shist[(k >> 16) & 0xFFu], 1u);
  }
  __syncthreads();
  uint32_t v = shist[t];
  if (v) atomicAdd(&fhist[b * 256 + t], v);
}

// K4: final 16-bit threshold beta = (cb<<8)|d:
// count(key>>16 > beta) < PRE_NMS <= count(key>>16 >= beta), finite keys only.
__global__ void k_thresh(const uint32_t* __restrict__ fhist,
                         const int* __restrict__ cbArr,
                         const uint32_t* __restrict__ cumArr,
                         uint32_t* __restrict__ thresh,
                         uint32_t* __restrict__ cnts) {
  int b = blockIdx.x;
  int t = threadIdx.x;  // 256
  __shared__ uint32_t sA[256];
  if (t < 2) cnts[b * CNT_STRIDE + t] = 0;
  int cb = cbArr[b];
  if (cb < 0) {
    if (t == 0) thresh[b] = 0u;
    return;
  }
  uint32_t cumAbove = cumArr[b];
  sA[t] = fhist[b * 256 + t];
  for (int d = 1; d < 256; d <<= 1) {
    __syncthreads();
    uint32_t v = sA[t] + ((t + d < 256) ? sA[t + d] : 0u);
    __syncthreads();
    sA[t] = v;
  }
  __syncthreads();
  uint32_t nxt = (t < 255) ? sA[t + 1] : 0u;
  if (cumAbove + sA[t] >= PRE_NMS && cumAbove + nxt < PRE_NMS)
    thresh[b] = (uint32_t)((cb << 8) | t);
}

// K5: gather candidate KEYS ONLY (8B each), block-aggregated atomics: one
// atomicAdd per category per block. Strictly-above fills [0, c1); ties fill
// from CAP-1 downward; overflow ties dropped (only above 2096 ties/batch).
// First SEL/256 blocks per batch also default-fill sel_box/sel_score.
__global__ void k_gather(const uint32_t* __restrict__ keys,
                         const uint32_t* __restrict__ thresh,
                         uint32_t* __restrict__ cnts,
                         unsigned long long* __restrict__ cand_sort,
                         float4* __restrict__ sel_box,
                         float* __restrict__ sel_score,
                         int A, int chunks) {
  int b = blockIdx.y;
  int t = threadIdx.x;  // 256
  int lane = t & 63;
  int w = t >> 6;  // wave 0..3
  if (blockIdx.x < SEL / 256) {  // folded k_fillsel
    int r = blockIdx.x * 256 + t;
    sel_score[(size_t)b * SEL + r] = -INFINITY;
    sel_box[(size_t)b * SEL + r] = make_float4(0.0f, 0.0f, 0.0f, 0.0f);
  }
  __shared__ unsigned long long s_mA[MAXCHUNK * 4], s_mT[MAXCHUNK * 4];
  __shared__ uint32_t s_offA[MAXCHUNK * 4], s_offT[MAXCHUNK * 4];
  __shared__ uint32_t s_cA[MAXCHUNK * 4], s_cT[MAXCHUNK * 4];
  __shared__ uint32_t s_baseA, s_baseT;
  uint32_t beta = thresh[b];
  uint32_t kreg[MAXCHUNK];
  int base_a = blockIdx.x * (chunks * 256);
  for (int c = 0; c < chunks; c++) {
    int a = base_a + c * 256 + t;
    bool inb = a < A;
    uint32_t k = inb ? keys[(size_t)b * A + a] : KEY_NEGINF;
    kreg[c] = k;
    uint32_t bk = k >> 16;
    bool fin = (k != KEY_NEGINF);
    unsigned long long mA = __ballot(fin && (bk > beta));
    unsigned long long mT = __ballot(fin && (bk == beta));
    if (lane == 0) {
      s_mA[c * 4 + w] = mA;
      s_mT[c * 4 + w] = mT;
    }
  }
  __syncthreads();
  if (t < chunks * 4) {
    s_cA[t] = (uint32_t)__popcll(s_mA[t]);
    s_cT[t] = (uint32_t)__popcll(s_mT[t]);
  }
  __syncthreads();
  if (t == 0) {  // serial scan over <=44 entries, then ONE atomic per category
    uint32_t accA = 0, accT = 0;
    for (int id = 0; id < chunks * 4; id++) {
      s_offA[id] = accA;
      accA += s_cA[id];
      s_offT[id] = accT;
      accT += s_cT[id];
    }
    s_baseA = accA ? atomicAdd(&cnts[b * CNT_STRIDE + 0], accA) : 0u;
    s_baseT = accT ? atomicAdd(&cnts[b * CNT_STRIDE + 1], accT) : 0u;
  }
  __syncthreads();
  uint32_t baseA = s_baseA, baseT = s_baseT;
  unsigned long long lower = ((unsigned long long)1 << lane) - 1;
  for (int c = 0; c < chunks; c++) {
    int id = c * 4 + w;
    unsigned long long mA = s_mA[id], mT = s_mT[id];
    bool above = (mA >> lane) & 1;
    bool tie = (mT >> lane) & 1;
    if (!(above || tie)) continue;
    int pos;
    if (above) {
      pos = (int)(baseA + s_offA[id] + (uint32_t)__popcll(mA & lower));
      if (pos >= PRE_NMS) continue;  // defensive; cannot happen
    } else {
      pos = CAP - 1 - (int)(baseT + s_offT[id] + (uint32_t)__popcll(mT & lower));
      if (pos < PRE_NMS) continue;  // drop overflow ties
    }
    int a = base_a + c * 256 + t;
    // sort key: (score_key desc, anchor index asc) via descending u64 order
    cand_sort[(size_t)b * CAP + pos] =
        ((unsigned long long)kreg[c] << 32) | (uint32_t)(~(uint32_t)a);
  }
}

// K6b: enumeration sort. Keys are strictly distinct ((score_key, ~anchor)),
// so rank = #{keys > mine} is the exact descending-sorted position. Each
// thread owns one slot, streams the batch's live slots through LDS broadcast
// tiles, and (if rank < SEL) decodes its box from the embedded anchor index.
// grid = (CAP/256, B). Fully parallel: 256 blocks, no cross-thread deps.
__global__ void k_rank(const unsigned long long* __restrict__ cand_sort,
                       const uint32_t* __restrict__ cnts,
                       const float4* __restrict__ anchors,
                       const float4* __restrict__ deltas,
                       float4* __restrict__ sel_box,
                       float* __restrict__ sel_score, int A) {
  int b = blockIdx.y;
  int t = threadIdx.x;  // 256
  uint32_t c1 = cnts[b * CNT_STRIDE + 0];
  if (c1 > PRE_NMS) c1 = PRE_NMS;
  uint32_t c2 = cnts[b * CNT_STRIDE + 1];
  if (c2 > CAP - PRE_NMS) c2 = CAP - PRE_NMS;
  int loTie = CAP - (int)c2;
  int bs = blockIdx.x * 256;
  if (bs >= (int)c1 && bs + 256 <= loTie) return;  // block fully in dead gap
  int s = bs + t;
  bool live = (s < (int)c1) || (s >= loTie);
  unsigned long long myKey = live ? cand_sort[(size_t)b * CAP + s] : 0ull;
  __shared__ unsigned long long tile[256];
  int rank = 0;
  for (int ts = 0; ts < CAP; ts += 256) {  // tile-skip is block-uniform
    if (ts >= (int)c1 && ts + 256 <= loTie) continue;
    int idx = ts + t;
    bool lv = (idx < (int)c1) || (idx >= loTie);
    __syncthreads();
    tile[t] = lv ? cand_sort[(size_t)b * CAP + idx] : 0ull;
    __syncthreads();
    if (live) {
#pragma unroll 8
      for (int j = 0; j < 256; j++) rank += (tile[j] > myKey) ? 1 : 0;
    }
  }
  if (live && rank < SEL) {
    uint32_t a = ~((uint32_t)myKey);
    float4 box = decode_clip(anchors[a], deltas[(size_t)b * A + a]);
    sel_score[(size_t)b * SEL + rank] = key2f((uint32_t)(myKey >> 32));
    sel_box[(size_t)b * SEL + rank] = box;
  }
}

// K7 (R20): suppression bitmask, COLUMN-TILE-MAJOR output mask[b][jb][i].
// Grid (2, NW, B), 1024 threads = 16 waves; block (qc, ib) covers col tiles
// jb = qc*16 + w (one per wave). 16-wave workgroups FORCE co-residency:
// 48 active blocks/batch, ~21KB LDS -> 2 blocks (32 waves) per CU. Body is
// R16's proven loop, unchanged. Lower-triangle waves idle after the barrier;
// fully-lower blocks (qc==0, ib>15) exit before any barrier. Diagonal wave
// also emits the transposed column word maskT. IoU identical to reference.
__global__ void __launch_bounds__(1024)
k_nmsmask(const float4* __restrict__ sel_box,
          unsigned long long* __restrict__ mask,
          unsigned long long* __restrict__ maskT) {
  int qc = blockIdx.x;  // col-tile group 0..1
  int ib = blockIdx.y;  // row block
  if (qc * 16 + 15 < ib) return;  // whole block below diagonal (uniform)
  int b = blockIdx.z;
  int t = threadIdx.x;  // 1024 = 16 waves
  int lane = t & 63;
  int w = t >> 6;
  int jb = qc * 16 + w;  // this wave's col tile (<= 31 always)
  __shared__ float4 rowb[64];
  __shared__ float rowarea[64];
  __shared__ float4 colb[16][64];
  __shared__ float colarea[16][64];
  if (t < 64) {
    float4 rb = sel_box[(size_t)b * SEL + ib * 64 + t];
    rowb[t] = rb;
    rowarea[t] = (rb.z - rb.x) * (rb.w - rb.y);
  }
  bool wvalid = (jb >= ib);
  if (wvalid) {
    float4 cbx = sel_box[(size_t)b * SEL + jb * 64 + lane];
    colb[w][lane] = cbx;
    colarea[w][lane] = (cbx.z - cbx.x) * (cbx.w - cbx.y);
  }
  __syncthreads();  // all 16 waves arrive; no barriers after this point
  if (!wvalid) return;
  float4 a = rowb[lane];
  float area_a = rowarea[lane];
  int i = ib * 64 + lane;
  unsigned long long bits = 0ull;
  if (i < PRE_NMS) {  // pad rows write zeros (never consumed anyway)
    bool diag = (jb == ib);
    int jmax = min(64, PRE_NMS - jb * 64);
    for (int jj = 0; jj < jmax; jj++) {
      if (diag && jj <= lane) continue;
      float4 bb = colb[w][jj];        // LDS broadcast
      float area_b = colarea[w][jj];  // precomputed
      float ltx = fmaxf(a.x, bb.x), lty = fmaxf(a.y, bb.y);
      float rbx = fminf(a.z, bb.z), rby = fminf(a.w, bb.w);
      float ww = fmaxf(rbx - ltx, 0.0f), hh = fmaxf(rby - lty, 0.0f);
      float inter = ww * hh;
      float iou = inter / (area_a + area_b - inter + 1e-6f);
      if (iou > NMS_THR) bits |= (1ull << jj);
    }
  }
  mask[((size_t)b * NW + jb) * SEL + i] = bits;  // coalesced 512B per wave
  if (jb == ib) {  // transpose the 64x64 diagonal block via ballots
    unsigned long long myT = 0ull;
#pragma unroll 1
    for (int jj = 0; jj < 64; jj++) {
      unsigned long long colw = __ballot((bits >> jj) & 1ull);
      if (lane == jj) myT = colw;
    }
    maskT[(size_t)b * SEL + i] = myT;
  }
}

// K8: one wave per batch. Per 64-row chunk: greedy NMS = grounded extension
// of the acyclic in-chunk attack DAG, computed by Jacobi iteration
//   K <- ballot(alive && (colm & K)==0)
// (unique fixpoint; converges in <= chain depth rounds, each ~1 ballot).
// Cross-chunk `removed` accumulates from a DOUBLE-BUFFERED LDS-DMA tile.
// Mask is column-tile-major; DMA op k fetches two 512B column segments
// (jb = 2k + lane>>5) into LDS tile [jb][row]. Accumulate: lane tw reads
// rows in staggered order jr=(j+tw)&63 with branchless per-lane bit masks;
// words tw < chunk are structurally zero (unwritten lower triangle) and
// masked out via wv.
__global__ void __launch_bounds__(64, 1)
k_scanout(const float4* __restrict__ sel_box,
          const float* __restrict__ sel_score,
          const unsigned long long* __restrict__ mask,
          const unsigned long long* __restrict__ maskT,
          float* __restrict__ out) {
  int b = blockIdx.x;
  int t = threadIdx.x;  // 64 = 1 wave
  int tw = t & 31;
  __shared__ uint32_t keptList[POST_NMS + 64];     // overshoot space
  __shared__ unsigned long long tile[2][64 * NW];  // [buf][jb*64 + row]
  unsigned long long removed = 0ull;  // lane w<32 owns word w (dup in w+32)
  int kc = 0;
  const unsigned long long* mb = mask + (size_t)b * NW * SEL;  // col-major
  const unsigned long long* tbase = maskT + (size_t)b * SEL;
  const int lastChunk = (PRE_NMS - 1) / 64;  // 31
  int cjb = t >> 5;        // column parity within a DMA op
  int ro = (t & 31) * 2;   // row offset (2 rows = 16B per lane)

  // prologue: DMA chunk 0 -> tile[0]; load chunk 0's colm + score
  {
#pragma unroll
    for (int k = 0; k < 16; k++) {
      const unsigned long long* gp =
          mb + ((size_t)(2 * k + cjb)) * SEL + ro;
      __builtin_amdgcn_global_load_lds(
          (const __attribute__((address_space(1))) uint32_t*)gp,
          (__attribute__((address_space(3))) uint32_t*)&tile[0][k * 128],
          16, 0, 0);
    }
  }
  unsigned long long colm = tbase[t];
  uint32_t scb = __float_as_uint(sel_score[(size_t)b * SEL + t]);

  for (int chunk = 0; chunk <= lastChunk; chunk++) {
    int cur = chunk & 1;
    // issue DMA for chunk+1 into the other buffer + prefetch its colm/score
    unsigned long long colm_n = 0ull;
    uint32_t scb_n = 0xFF800000u;
    if (chunk < lastChunk) {
#pragma unroll
      for (int k = 0; k < 16; k++) {
        const unsigned long long* gp =
            mb + ((size_t)(2 * k + cjb)) * SEL + (size_t)(chunk + 1) * 64 + ro;
        __builtin_amdgcn_global_load_lds(
            (const __attribute__((address_space(1))) uint32_t*)gp,
            (__attribute__((address_space(3))) uint32_t*)
                &tile[cur ^ 1][k * 128],
            16, 0, 0);
      }
      colm_n = tbase[(chunk + 1) * 64 + t];
      scb_n =
          __float_as_uint(sel_score[(size_t)b * SEL + (chunk + 1) * 64 + t]);
    }
    int rmax = PRE_NMS - chunk * 64;
    if (rmax > 64) rmax = 64;
    unsigned long long vb = __ballot(scb != 0xFF800000u);
    unsigned long long curw = readlane_u64(removed, chunk);
    unsigned long long range = (rmax >= 64) ? ~0ull : ((1ull << rmax) - 1ull);
    unsigned long long alive0 = ~curw & range;
    // Jacobi fixpoint: K_{n+1}[j] = alive0[j] && (colm[j] & K_n)==0.
    unsigned long long K = alive0;
    bool aliveb = (alive0 >> t) & 1ull;
#pragma unroll 1
    for (int it = 0; it < 64; ++it) {
      bool deadb = (colm & K) != 0ull;
      unsigned long long Kn = __ballot(aliveb && !deadb);
      if (Kn == K) break;
      K = Kn;
    }
    unsigned long long keptbits = K;
    // bookkeeping: lane-parallel keptList append via popcount rank
    unsigned long long kv = keptbits & vb;
    if ((kv >> t) & 1ull) {
      int rank = (int)__popcll(kv & ((1ull << t) - 1ull));
      keptList[kc + rank] = (uint32_t)(chunk * 64 + t);
    }
    kc += (int)__popcll(kv);
    if (kc >= POST_NMS) break;      // future chunks irrelevant
    if (chunk == lastChunk) break;  // no future chunks
    // Drain this chunk's tile DMA (issued LAST iteration; fully overlapped).
    // Newest 18 VMEM ops (this iteration's 16 DMA + colm_n + scb_n) may
    // remain outstanding.
    asm volatile("s_waitcnt vmcnt(18)" ::: "memory");
    __builtin_amdgcn_sched_barrier(0);
    // accumulate removed: lane tw owns word tw = column tw; read rows in
    // staggered order jr=(j+tw)&63, branchless bit masks.
    unsigned long long acc = 0ull;
#pragma unroll
    for (int j = 0; j < 64; j++) {
      int jr = (j + tw) & 63;
      unsigned long long v = tile[cur][tw * 64 + jr];
      unsigned long long mk =
          (unsigned long long)(-(long long)((keptbits >> jr) & 1ull));
      acc |= v & mk;
    }
    // words tw < chunk are structurally zero (unwritten lower triangle)
    unsigned long long wv = (tw >= chunk) ? ~0ull : 0ull;
    removed |= acc & wv;
    // keep next iteration's DMA (overwrites tile[cur]) below these ds_reads
    __builtin_amdgcn_sched_barrier(0);
    colm = colm_n;
    scb = scb_n;
  }
  int kcc = kc < POST_NMS ? kc : POST_NMS;
  __syncthreads();
  for (int r = t; r < POST_NMS; r += 64) {
    float4 bx = make_float4(0.0f, 0.0f, 0.0f, 0.0f);
    float sc = 0.0f;
    if (r < kcc) {
      int i = (int)keptList[r];
      bx = sel_box[(size_t)b * SEL + i];
      sc = sel_score[(size_t)b * SEL + i];
    }
    float* o = out + ((size_t)b * POST_NMS + r) * 5;
    o[0] = bx.x;
    o[1] = bx.y;
    o[2] = bx.z;
    o[3] = bx.w;
    o[4] = sc;
  }
}

extern "C" void kernel_launch(void* const* d_in, const int* in_sizes, int n_in,
                              void* d_out, int out_size, void* d_ws, size_t ws_size,
                              hipStream_t stream) {
  const float* anchors = (const float*)d_in[0];  // (A, 4)
  const float* deltas = (const float*)d_in[1];   // (B, A, 4)
  const float* scores = (const float*)d_in[2];   // (B, A)
  int A = in_sizes[0] / 4;
  int BA = in_sizes[2];
  int B = BA / A;
  float* out = (float*)d_out;

  char* ws = (char*)d_ws;
  size_t off = 0;
  uint32_t* keys = (uint32_t*)(ws + off);
  off += (size_t)BA * 4;
  uint32_t* chist = (uint32_t*)(ws + off);
  off += (size_t)B * 256 * 4;
  uint32_t* fhist = (uint32_t*)(ws + off);
  off += (size_t)B * 256 * 4;
  int* cbArr = (int*)(ws + off);
  off += (size_t)B * 4;
  uint32_t* cumArr = (uint32_t*)(ws + off);
  off += (size_t)B * 4;
  uint32_t* thresh = (uint32_t*)(ws + off);
  off += (size_t)B * 4;
  off = (off + 127) & ~(size_t)127;
  uint32_t* cnts = (uint32_t*)(ws + off);
  off += (size_t)B * CNT_STRIDE * 4;
  off = (off + 15) & ~(size_t)15;
  unsigned long long* cand_sort = (unsigned long long*)(ws + off);
  off += (size_t)B * CAP * 8;
  float4* sel_box = (float4*)(ws + off);
  off += (size_t)B * SEL * 16;
  float* sel_score = (float*)(ws + off);
  off += (size_t)B * SEL * 4;
  unsigned long long* mask = (unsigned long long*)(ws + off);
  off += (size_t)B * NW * SEL * 8;  // column-tile-major [B][NW][SEL]
  unsigned long long* maskT = (unsigned long long*)(ws + off);
  off += (size_t)B * SEL * 8;  // 256 KB
  // total ~27.3 MB

  // Block geometry for per-batch streaming kernels: A = 261888 = 256*11*93.
  int chunks = (A % (256 * 11) == 0) ? 11 : 1;
  int bpb = (A + 256 * chunks - 1) / (256 * chunks);  // blocks per batch

  hipMemsetAsync(chist, 0, (size_t)B * 256 * 4 * 2, stream);  // chist+fhist
  k_decode<<<dim3(bpb, B), 256, 0, stream>>>((const float4*)anchors,
                                             (const float4*)deltas, scores,
                                             keys, chist, A, chunks);
  k_coarse<<<B, 256, 0, stream>>>(chist, cbArr, cumArr);
  k_fine<<<dim3(bpb, B), 256, 0, stream>>>(keys, cbArr, fhist, A, chunks);
  k_thresh<<<B, 256, 0, stream>>>(fhist, cbArr, cumArr, thresh, cnts);
  k_gather<<<dim3(bpb, B), 256, 0, stream>>>(keys, thresh, cnts, cand_sort,
                                             sel_box, sel_score, A, chunks);
  k_rank<<<dim3(CAP / 256, B), 256, 0, stream>>>(cand_sort, cnts,
                                                 (const float4*)anchors,
                                                 (const float4*)deltas,
                                                 sel_box, sel_score, A);
  k_nmsmask<<<dim3(2, NW, B), 1024, 0, stream>>>(sel_box, mask, maskT);
  k_scanout<<<B, 64, 0, stream>>>(sel_box, sel_score, mask, maskT, out);
}

// Round 15
// 279.305 us; speedup vs baseline: 1.0332x; 1.0332x over previous
//
#include <hip/hip_runtime.h>
#include <stdint.h>
#include <math.h>

// RPN proposal filtering: decode -> clip -> validity mask -> stable top-2000
// -> greedy NMS (IoU > 0.7) -> first 1000 kept -> (B, 1000, 5).
//
// R21: k_nmsmask IEEE-div ELIMINATED (exactly). Five structures converged at
// ~56us / ~50% VALU duty (R15 1-wave, R16 4-wave, R18 unroll, R19 4-chain,
// R20 forced 16-wave residency). Common invariant: the fp32 IEEE division,
// which on gfx950 is ~10 instrs with a VCC live range (v_div_scale writes
// VCC, v_div_fmas reads it) -> independent divs can't overlap; ~40cy serial
// chain per IoU = the 50% duty cap. Replacement (bit-exact):
//   fl32(inter/denom) > 0.7f  <=>  inter/denom >= T,  T = 0.7f + 2^-25
// (0.7f mantissa odd -> RNE boundary at c+ulp/2), and with denom > 0
// (clip guarantees x1<=x2 -> areas>=0 -> denom>=1e-6):
//   <=>  (double)inter >= T*(double)denom   [T:25b x denom:24b = 49b EXACT]
// 4 instrs (2 cvt, mul_f64, cmp_f64), no VCC liveness, 3-deep chain.
// Structure = R16's proven kernel unchanged (single-variable test).

#define IMGF 1024.0f
#define PRE_NMS 2000
#define POST_NMS 1000
#define NMS_THR 0.7f
#define MIN_SZ 16.0f
#define CAP 4096          // candidate buffer per batch
#define SEL 2048          // padded selection stride (>= PRE_NMS)
#define NW (SEL / 64)     // 32 mask words per row
#define CNT_STRIDE 32     // u32s per batch for counters (128 B -> own line)
#define KEY_NEGINF 0x007FFFFFu  // f2key(-inf)
#define MAXCHUNK 12
// fl32(x/y) > 0.7f  <=>  x >= IOU_T * y  (y > 0); exact in double.
#define IOU_T 0x1.6666668p-1

// Order-preserving float -> u32 key (all floats incl. -inf totally ordered).
__device__ __forceinline__ uint32_t f2key(float f) {
  uint32_t u = __float_as_uint(f);
  return (u & 0x80000000u) ? ~u : (u | 0x80000000u);
}
__device__ __forceinline__ float key2f(uint32_t k) {
  uint32_t u = (k & 0x80000000u) ? (k & 0x7FFFFFFFu) : ~k;
  return __uint_as_float(u);
}

__device__ __forceinline__ unsigned long long readlane_u64(unsigned long long v,
                                                           int lane) {
  unsigned int lo = __builtin_amdgcn_readlane((unsigned int)v, lane);
  unsigned int hi = __builtin_amdgcn_readlane((unsigned int)(v >> 32), lane);
  return ((unsigned long long)hi << 32) | lo;
}

// Mirrors reference _decode + clip, fp32.
__device__ __forceinline__ float4 decode_clip(float4 anc, float4 dlt) {
  float aw = anc.z - anc.x;
  float ah = anc.w - anc.y;
  float ax = anc.x + 0.5f * aw;
  float ay = anc.y + 0.5f * ah;
  float dw = fminf(dlt.z, 4.0f);
  float dh = fminf(dlt.w, 4.0f);
  float px = dlt.x * aw + ax;
  float py = dlt.y * ah + ay;
  float pw = expf(dw) * aw;
  float ph = expf(dh) * ah;
  float x1 = px - 0.5f * pw, y1 = py - 0.5f * ph;
  float x2 = px + 0.5f * pw, y2 = py + 0.5f * ph;
  x1 = fminf(fmaxf(x1, 0.0f), IMGF);
  y1 = fminf(fmaxf(y1, 0.0f), IMGF);
  x2 = fminf(fmaxf(x2, 0.0f), IMGF);
  y2 = fminf(fmaxf(y2, 0.0f), IMGF);
  return make_float4(x1, y1, x2, y2);
}

// K1: decode -> masked-score key; per-block LDS coarse hist of key>>24
// (finite keys only), ballot-match wave aggregation, one aggregated global
// flush per block. grid = (bpb, B).
__global__ void k_decode(const float4* __restrict__ anchors,
                         const float4* __restrict__ deltas,
                         const float* __restrict__ scores,
                         uint32_t* __restrict__ keys,
                         uint32_t* __restrict__ chist,
                         int A, int chunks) {
  int b = blockIdx.y;
  int t = threadIdx.x;  // 256
  int lane = t & 63;
  __shared__ uint32_t shist[256];
  shist[t] = 0;
  __syncthreads();
  int base_a = blockIdx.x * (chunks * 256);
  for (int c = 0; c < chunks; c++) {
    int a = base_a + c * 256 + t;
    bool inb = a < A;
    int ac = inb ? a : (A - 1);
    size_t i = (size_t)b * A + ac;
    float4 box = decode_clip(anchors[ac], deltas[i]);
    bool valid = (box.z - box.x >= MIN_SZ) && (box.w - box.y >= MIN_SZ);
    float ms = valid ? scores[i] : -INFINITY;
    uint32_t k = f2key(ms);
    if (inb) keys[i] = k;
    uint32_t bucket = k >> 24;
    bool fin = inb && (k != KEY_NEGINF);
    // lanes with equal bucket -> one LDS atomic by the leader
    unsigned long long match = __ballot(fin);
#pragma unroll
    for (int bit = 0; bit < 8; bit++) {
      bool hb = (bucket >> bit) & 1;
      unsigned long long bb = __ballot(hb && fin);
      match &= hb ? bb : ~bb;
    }
    if (fin && (__ffsll((long long)match) - 1 == lane))
      atomicAdd(&shist[bucket], (uint32_t)__popcll(match));
  }
  __syncthreads();
  uint32_t v = shist[t];
  if (v) atomicAdd(&chist[b * 256 + t], v);
}

// K2: pick coarse bucket cb s.t. countAbove(cb) < PRE_NMS <= countAbove(cb)+chist[cb].
__global__ void k_coarse(const uint32_t* __restrict__ chist,
                         int* __restrict__ cbArr,
                         uint32_t* __restrict__ cumArr) {
  int b = blockIdx.x;
  int t = threadIdx.x;  // 256
  __shared__ uint32_t sA[256];
  sA[t] = chist[b * 256 + t];
  for (int d = 1; d < 256; d <<= 1) {  // inclusive suffix scan
    __syncthreads();
    uint32_t v = sA[t] + ((t + d < 256) ? sA[t + d] : 0u);
    __syncthreads();
    sA[t] = v;
  }
  __syncthreads();
  if (t == 0 && sA[0] < PRE_NMS) {  // degenerate: < PRE_NMS finite entries
    cbArr[b] = -1;
    cumArr[b] = 0;
  }
  uint32_t nxt = (t < 255) ? sA[t + 1] : 0u;
  if (sA[t] >= PRE_NMS && nxt < PRE_NMS) {
    cbArr[b] = t;
    cumArr[b] = nxt;  // count strictly above coarse bucket t
  }
}

// K3: fine hist of key bits[23:16] for elements whose coarse bucket == cb[b].
__global__ void k_fine(const uint32_t* __restrict__ keys,
                       const int* __restrict__ cbArr,
                       uint32_t* __restrict__ fhist,
                       int A, int chunks) {
  int b = blockIdx.y;
  int t = threadIdx.x;  // 256
  int cb = cbArr[b];
  if (cb < 0) return;
  __shared__ uint32_t shist[256];
  shist[t] = 0;
  __syncthreads();
  int base_a = blockIdx.x * (chunks * 256);
  uint32_t cbu = (uint32_t)cb;
  for (int c = 0; c < chunks; c++) {
    int a = base_a + c * 256 + t;
    if (a >= A) break;
    uint32_t k = keys[(size_t)b * A + a];
    if ((k >> 24) == cbu && k != KEY_NEGINF)
      atomicAdd(&shist[(k >> 16) & 0xFFu], 1u);
  }
  __syncthreads();
  uint32_t v = shist[t];
  if (v) atomicAdd(&fhist[b * 256 + t], v);
}

// K4: final 16-bit threshold beta = (cb<<8)|d:
// count(key>>16 > beta) < PRE_NMS <= count(key>>16 >= beta), finite keys only.
__global__ void k_thresh(const uint32_t* __restrict__ fhist,
                         const int* __restrict__ cbArr,
                         const uint32_t* __restrict__ cumArr,
                         uint32_t* __restrict__ thresh,
                         uint32_t* __restrict__ cnts) {
  int b = blockIdx.x;
  int t = threadIdx.x;  // 256
  __shared__ uint32_t sA[256];
  if (t < 2) cnts[b * CNT_STRIDE + t] = 0;
  int cb = cbArr[b];
  if (cb < 0) {
    if (t == 0) thresh[b] = 0u;
    return;
  }
  uint32_t cumAbove = cumArr[b];
  sA[t] = fhist[b * 256 + t];
  for (int d = 1; d < 256; d <<= 1) {
    __syncthreads();
    uint32_t v = sA[t] + ((t + d < 256) ? sA[t + d] : 0u);
    __syncthreads();
    sA[t] = v;
  }
  __syncthreads();
  uint32_t nxt = (t < 255) ? sA[t + 1] : 0u;
  if (cumAbove + sA[t] >= PRE_NMS && cumAbove + nxt < PRE_NMS)
    thresh[b] = (uint32_t)((cb << 8) | t);
}

// K5: gather candidate KEYS ONLY (8B each), block-aggregated atomics: one
// atomicAdd per category per block. Strictly-above fills [0, c1); ties fill
// from CAP-1 downward; overflow ties dropped (only above 2096 ties/batch).
// First SEL/256 blocks per batch also default-fill sel_box/sel_score.
__global__ void k_gather(const uint32_t* __restrict__ keys,
                         const uint32_t* __restrict__ thresh,
                         uint32_t* __restrict__ cnts,
                         unsigned long long* __restrict__ cand_sort,
                         float4* __restrict__ sel_box,
                         float* __restrict__ sel_score,
                         int A, int chunks) {
  int b = blockIdx.y;
  int t = threadIdx.x;  // 256
  int lane = t & 63;
  int w = t >> 6;  // wave 0..3
  if (blockIdx.x < SEL / 256) {  // folded k_fillsel
    int r = blockIdx.x * 256 + t;
    sel_score[(size_t)b * SEL + r] = -INFINITY;
    sel_box[(size_t)b * SEL + r] = make_float4(0.0f, 0.0f, 0.0f, 0.0f);
  }
  __shared__ unsigned long long s_mA[MAXCHUNK * 4], s_mT[MAXCHUNK * 4];
  __shared__ uint32_t s_offA[MAXCHUNK * 4], s_offT[MAXCHUNK * 4];
  __shared__ uint32_t s_cA[MAXCHUNK * 4], s_cT[MAXCHUNK * 4];
  __shared__ uint32_t s_baseA, s_baseT;
  uint32_t beta = thresh[b];
  uint32_t kreg[MAXCHUNK];
  int base_a = blockIdx.x * (chunks * 256);
  for (int c = 0; c < chunks; c++) {
    int a = base_a + c * 256 + t;
    bool inb = a < A;
    uint32_t k = inb ? keys[(size_t)b * A + a] : KEY_NEGINF;
    kreg[c] = k;
    uint32_t bk = k >> 16;
    bool fin = (k != KEY_NEGINF);
    unsigned long long mA = __ballot(fin && (bk > beta));
    unsigned long long mT = __ballot(fin && (bk == beta));
    if (lane == 0) {
      s_mA[c * 4 + w] = mA;
      s_mT[c * 4 + w] = mT;
    }
  }
  __syncthreads();
  if (t < chunks * 4) {
    s_cA[t] = (uint32_t)__popcll(s_mA[t]);
    s_cT[t] = (uint32_t)__popcll(s_mT[t]);
  }
  __syncthreads();
  if (t == 0) {  // serial scan over <=44 entries, then ONE atomic per category
    uint32_t accA = 0, accT = 0;
    for (int id = 0; id < chunks * 4; id++) {
      s_offA[id] = accA;
      accA += s_cA[id];
      s_offT[id] = accT;
      accT += s_cT[id];
    }
    s_baseA = accA ? atomicAdd(&cnts[b * CNT_STRIDE + 0], accA) : 0u;
    s_baseT = accT ? atomicAdd(&cnts[b * CNT_STRIDE + 1], accT) : 0u;
  }
  __syncthreads();
  uint32_t baseA = s_baseA, baseT = s_baseT;
  unsigned long long lower = ((unsigned long long)1 << lane) - 1;
  for (int c = 0; c < chunks; c++) {
    int id = c * 4 + w;
    unsigned long long mA = s_mA[id], mT = s_mT[id];
    bool above = (mA >> lane) & 1;
    bool tie = (mT >> lane) & 1;
    if (!(above || tie)) continue;
    int pos;
    if (above) {
      pos = (int)(baseA + s_offA[id] + (uint32_t)__popcll(mA & lower));
      if (pos >= PRE_NMS) continue;  // defensive; cannot happen
    } else {
      pos = CAP - 1 - (int)(baseT + s_offT[id] + (uint32_t)__popcll(mT & lower));
      if (pos < PRE_NMS) continue;  // drop overflow ties
    }
    int a = base_a + c * 256 + t;
    // sort key: (score_key desc, anchor index asc) via descending u64 order
    cand_sort[(size_t)b * CAP + pos] =
        ((unsigned long long)kreg[c] << 32) | (uint32_t)(~(uint32_t)a);
  }
}

// K6b: enumeration sort. Keys are strictly distinct ((score_key, ~anchor)),
// so rank = #{keys > mine} is the exact descending-sorted position. Each
// thread owns one slot, streams the batch's live slots through LDS broadcast
// tiles, and (if rank < SEL) decodes its box from the embedded anchor index.
// grid = (CAP/256, B). Fully parallel: 256 blocks, no cross-thread deps.
__global__ void k_rank(const unsigned long long* __restrict__ cand_sort,
                       const uint32_t* __restrict__ cnts,
                       const float4* __restrict__ anchors,
                       const float4* __restrict__ deltas,
                       float4* __restrict__ sel_box,
                       float* __restrict__ sel_score, int A) {
  int b = blockIdx.y;
  int t = threadIdx.x;  // 256
  uint32_t c1 = cnts[b * CNT_STRIDE + 0];
  if (c1 > PRE_NMS) c1 = PRE_NMS;
  uint32_t c2 = cnts[b * CNT_STRIDE + 1];
  if (c2 > CAP - PRE_NMS) c2 = CAP - PRE_NMS;
  int loTie = CAP - (int)c2;
  int bs = blockIdx.x * 256;
  if (bs >= (int)c1 && bs + 256 <= loTie) return;  // block fully in dead gap
  int s = bs + t;
  bool live = (s < (int)c1) || (s >= loTie);
  unsigned long long myKey = live ? cand_sort[(size_t)b * CAP + s] : 0ull;
  __shared__ unsigned long long tile[256];
  int rank = 0;
  for (int ts = 0; ts < CAP; ts += 256) {  // tile-skip is block-uniform
    if (ts >= (int)c1 && ts + 256 <= loTie) continue;
    int idx = ts + t;
    bool lv = (idx < (int)c1) || (idx >= loTie);
    __syncthreads();
    tile[t] = lv ? cand_sort[(size_t)b * CAP + idx] : 0ull;
    __syncthreads();
    if (live) {
#pragma unroll 8
      for (int j = 0; j < 256; j++) rank += (tile[j] > myKey) ? 1 : 0;
    }
  }
  if (live && rank < SEL) {
    uint32_t a = ~((uint32_t)myKey);
    float4 box = decode_clip(anchors[a], deltas[(size_t)b * A + a]);
    sel_score[(size_t)b * SEL + rank] = key2f((uint32_t)(myKey >> 32));
    sel_box[(size_t)b * SEL + rank] = box;
  }
}

// K7 (R21): suppression bitmask, COLUMN-TILE-MAJOR output mask[b][jb][i].
// Grid (8, NW, B), 256 threads = 4 waves; block (qb, ib) covers col-tile
// quad jb = qb*4 + w, one tile per wave (R16's proven structure). The IoU
// decision uses the EXACT division-free comparison (see file header):
//   fl32(inter/denom) > 0.7f  <=>  (double)inter >= IOU_T*(double)denom
// -- removes the VCC-serialized ~10-instr IEEE div chain, the suspected
// ~50%-duty cap common to all five prior variants. Everything else
// (layout, maskT ballot transpose, pad semantics) unchanged.
__global__ void __launch_bounds__(256)
k_nmsmask(const float4* __restrict__ sel_box,
          unsigned long long* __restrict__ mask,
          unsigned long long* __restrict__ maskT) {
  int qb = blockIdx.x;  // col-tile quad 0..7
  int ib = blockIdx.y;  // row block
  if (qb * 4 + 3 < ib) return;  // whole quad below diagonal (uniform, pre-barrier)
  int b = blockIdx.z;
  int t = threadIdx.x;  // 256 = 4 waves
  int lane = t & 63;
  int w = t >> 6;
  int jb = qb * 4 + w;  // this wave's col tile (<= 31 always)
  __shared__ float4 rowb[64];
  __shared__ float rowarea[64];
  __shared__ float4 colb[4][64];
  __shared__ float colarea[4][64];
  if (t < 64) {
    float4 rb = sel_box[(size_t)b * SEL + ib * 64 + t];
    rowb[t] = rb;
    rowarea[t] = (rb.z - rb.x) * (rb.w - rb.y);
  }
  bool wvalid = (jb >= ib);
  if (wvalid) {
    float4 cbx = sel_box[(size_t)b * SEL + jb * 64 + lane];
    colb[w][lane] = cbx;
    colarea[w][lane] = (cbx.z - cbx.x) * (cbx.w - cbx.y);
  }
  __syncthreads();  // all 4 waves arrive; no barriers after this point
  if (!wvalid) return;
  float4 a = rowb[lane];
  float area_a = rowarea[lane];
  int i = ib * 64 + lane;
  unsigned long long bits = 0ull;
  if (i < PRE_NMS) {  // pad rows write zeros (never consumed anyway)
    bool diag = (jb == ib);
    int jmax = min(64, PRE_NMS - jb * 64);
    for (int jj = 0; jj < jmax; jj++) {
      if (diag && jj <= lane) continue;
      float4 bb = colb[w][jj];        // LDS broadcast
      float area_b = colarea[w][jj];  // precomputed
      float ltx = fmaxf(a.x, bb.x), lty = fmaxf(a.y, bb.y);
      float rbx = fminf(a.z, bb.z), rby = fminf(a.w, bb.w);
      float ww = fmaxf(rbx - ltx, 0.0f), hh = fmaxf(rby - lty, 0.0f);
      float inter = ww * hh;
      float denom = area_a + area_b - inter + 1e-6f;
      // denom > 0 structurally (clip keeps x1<=x2 -> areas >= 0, +1e-6).
      // Exact replacement for fl32(inter/denom) > 0.7f:
      if ((double)inter >= IOU_T * (double)denom) bits |= (1ull << jj);
    }
  }
  mask[((size_t)b * NW + jb) * SEL + i] = bits;  // coalesced 512B per wave
  if (jb == ib) {  // transpose the 64x64 diagonal block via ballots
    unsigned long long myT = 0ull;
#pragma unroll 1
    for (int jj = 0; jj < 64; jj++) {
      unsigned long long colw = __ballot((bits >> jj) & 1ull);
      if (lane == jj) myT = colw;
    }
    maskT[(size_t)b * SEL + i] = myT;
  }
}

// K8: one wave per batch. Per 64-row chunk: greedy NMS = grounded extension
// of the acyclic in-chunk attack DAG, computed by Jacobi iteration
//   K <- ballot(alive && (colm & K)==0)
// (unique fixpoint; converges in <= chain depth rounds, each ~1 ballot).
// Cross-chunk `removed` accumulates from a DOUBLE-BUFFERED LDS-DMA tile.
// Mask is column-tile-major; DMA op k fetches two 512B column segments
// (jb = 2k + lane>>5) into LDS tile [jb][row]. Accumulate: lane tw reads
// rows in staggered order jr=(j+tw)&63 with branchless per-lane bit masks;
// words tw < chunk are structurally zero (unwritten lower triangle) and
// masked out via wv.
__global__ void __launch_bounds__(64, 1)
k_scanout(const float4* __restrict__ sel_box,
          const float* __restrict__ sel_score,
          const unsigned long long* __restrict__ mask,
          const unsigned long long* __restrict__ maskT,
          float* __restrict__ out) {
  int b = blockIdx.x;
  int t = threadIdx.x;  // 64 = 1 wave
  int tw = t & 31;
  __shared__ uint32_t keptList[POST_NMS + 64];     // overshoot space
  __shared__ unsigned long long tile[2][64 * NW];  // [buf][jb*64 + row]
  unsigned long long removed = 0ull;  // lane w<32 owns word w (dup in w+32)
  int kc = 0;
  const unsigned long long* mb = mask + (size_t)b * NW * SEL;  // col-major
  const unsigned long long* tbase = maskT + (size_t)b * SEL;
  const int lastChunk = (PRE_NMS - 1) / 64;  // 31
  int cjb = t >> 5;        // column parity within a DMA op
  int ro = (t & 31) * 2;   // row offset (2 rows = 16B per lane)

  // prologue: DMA chunk 0 -> tile[0]; load chunk 0's colm + score
  {
#pragma unroll
    for (int k = 0; k < 16; k++) {
      const unsigned long long* gp =
          mb + ((size_t)(2 * k + cjb)) * SEL + ro;
      __builtin_amdgcn_global_load_lds(
          (const __attribute__((address_space(1))) uint32_t*)gp,
          (__attribute__((address_space(3))) uint32_t*)&tile[0][k * 128],
          16, 0, 0);
    }
  }
  unsigned long long colm = tbase[t];
  uint32_t scb = __float_as_uint(sel_score[(size_t)b * SEL + t]);

  for (int chunk = 0; chunk <= lastChunk; chunk++) {
    int cur = chunk & 1;
    // issue DMA for chunk+1 into the other buffer + prefetch its colm/score
    unsigned long long colm_n = 0ull;
    uint32_t scb_n = 0xFF800000u;
    if (chunk < lastChunk) {
#pragma unroll
      for (int k = 0; k < 16; k++) {
        const unsigned long long* gp =
            mb + ((size_t)(2 * k + cjb)) * SEL + (size_t)(chunk + 1) * 64 + ro;
        __builtin_amdgcn_global_load_lds(
            (const __attribute__((address_space(1))) uint32_t*)gp,
            (__attribute__((address_space(3))) uint32_t*)
                &tile[cur ^ 1][k * 128],
            16, 0, 0);
      }
      colm_n = tbase[(chunk + 1) * 64 + t];
      scb_n =
          __float_as_uint(sel_score[(size_t)b * SEL + (chunk + 1) * 64 + t]);
    }
    int rmax = PRE_NMS - chunk * 64;
    if (rmax > 64) rmax = 64;
    unsigned long long vb = __ballot(scb != 0xFF800000u);
    unsigned long long curw = readlane_u64(removed, chunk);
    unsigned long long range = (rmax >= 64) ? ~0ull : ((1ull << rmax) - 1ull);
    unsigned long long alive0 = ~curw & range;
    // Jacobi fixpoint: K_{n+1}[j] = alive0[j] && (colm[j] & K_n)==0.
    unsigned long long K = alive0;
    bool aliveb = (alive0 >> t) & 1ull;
#pragma unroll 1
    for (int it = 0; it < 64; ++it) {
      bool deadb = (colm & K) != 0ull;
      unsigned long long Kn = __ballot(aliveb && !deadb);
      if (Kn == K) break;
      K = Kn;
    }
    unsigned long long keptbits = K;
    // bookkeeping: lane-parallel keptList append via popcount rank
    unsigned long long kv = keptbits & vb;
    if ((kv >> t) & 1ull) {
      int rank = (int)__popcll(kv & ((1ull << t) - 1ull));
      keptList[kc + rank] = (uint32_t)(chunk * 64 + t);
    }
    kc += (int)__popcll(kv);
    if (kc >= POST_NMS) break;      // future chunks irrelevant
    if (chunk == lastChunk) break;  // no future chunks
    // Drain this chunk's tile DMA (issued LAST iteration; fully overlapped).
    // Newest 18 VMEM ops (this iteration's 16 DMA + colm_n + scb_n) may
    // remain outstanding.
    asm volatile("s_waitcnt vmcnt(18)" ::: "memory");
    __builtin_amdgcn_sched_barrier(0);
    // accumulate removed: lane tw owns word tw = column tw; read rows in
    // staggered order jr=(j+tw)&63, branchless bit masks.
    unsigned long long acc = 0ull;
#pragma unroll
    for (int j = 0; j < 64; j++) {
      int jr = (j + tw) & 63;
      unsigned long long v = tile[cur][tw * 64 + jr];
      unsigned long long mk =
          (unsigned long long)(-(long long)((keptbits >> jr) & 1ull));
      acc |= v & mk;
    }
    // words tw < chunk are structurally zero (unwritten lower triangle)
    unsigned long long wv = (tw >= chunk) ? ~0ull : 0ull;
    removed |= acc & wv;
    // keep next iteration's DMA (overwrites tile[cur]) below these ds_reads
    __builtin_amdgcn_sched_barrier(0);
    colm = colm_n;
    scb = scb_n;
  }
  int kcc = kc < POST_NMS ? kc : POST_NMS;
  __syncthreads();
  for (int r = t; r < POST_NMS; r += 64) {
    float4 bx = make_float4(0.0f, 0.0f, 0.0f, 0.0f);
    float sc = 0.0f;
    if (r < kcc) {
      int i = (int)keptList[r];
      bx = sel_box[(size_t)b * SEL + i];
      sc = sel_score[(size_t)b * SEL + i];
    }
    float* o = out + ((size_t)b * POST_NMS + r) * 5;
    o[0] = bx.x;
    o[1] = bx.y;
    o[2] = bx.z;
    o[3] = bx.w;
    o[4] = sc;
  }
}

extern "C" void kernel_launch(void* const* d_in, const int* in_sizes, int n_in,
                              void* d_out, int out_size, void* d_ws, size_t ws_size,
                              hipStream_t stream) {
  const float* anchors = (const float*)d_in[0];  // (A, 4)
  const float* deltas = (const float*)d_in[1];   // (B, A, 4)
  const float* scores = (const float*)d_in[2];   // (B, A)
  int A = in_sizes[0] / 4;
  int BA = in_sizes[2];
  int B = BA / A;
  float* out = (float*)d_out;

  char* ws = (char*)d_ws;
  size_t off = 0;
  uint32_t* keys = (uint32_t*)(ws + off);
  off += (size_t)BA * 4;
  uint32_t* chist = (uint32_t*)(ws + off);
  off += (size_t)B * 256 * 4;
  uint32_t* fhist = (uint32_t*)(ws + off);
  off += (size_t)B * 256 * 4;
  int* cbArr = (int*)(ws + off);
  off += (size_t)B * 4;
  uint32_t* cumArr = (uint32_t*)(ws + off);
  off += (size_t)B * 4;
  uint32_t* thresh = (uint32_t*)(ws + off);
  off += (size_t)B * 4;
  off = (off + 127) & ~(size_t)127;
  uint32_t* cnts = (uint32_t*)(ws + off);
  off += (size_t)B * CNT_STRIDE * 4;
  off = (off + 15) & ~(size_t)15;
  unsigned long long* cand_sort = (unsigned long long*)(ws + off);
  off += (size_t)B * CAP * 8;
  float4* sel_box = (float4*)(ws + off);
  off += (size_t)B * SEL * 16;
  float* sel_score = (float*)(ws + off);
  off += (size_t)B * SEL * 4;
  unsigned long long* mask = (unsigned long long*)(ws + off);
  off += (size_t)B * NW * SEL * 8;  // column-tile-major [B][NW][SEL]
  unsigned long long* maskT = (unsigned long long*)(ws + off);
  off += (size_t)B * SEL * 8;  // 256 KB
  // total ~27.3 MB

  // Block geometry for per-batch streaming kernels: A = 261888 = 256*11*93.
  int chunks = (A % (256 * 11) == 0) ? 11 : 1;
  int bpb = (A + 256 * chunks - 1) / (256 * chunks);  // blocks per batch

  hipMemsetAsync(chist, 0, (size_t)B * 256 * 4 * 2, stream);  // chist+fhist
  k_decode<<<dim3(bpb, B), 256, 0, stream>>>((const float4*)anchors,
                                             (const float4*)deltas, scores,
                                             keys, chist, A, chunks);
  k_coarse<<<B, 256, 0, stream>>>(chist, cbArr, cumArr);
  k_fine<<<dim3(bpb, B), 256, 0, stream>>>(keys, cbArr, fhist, A, chunks);
  k_thresh<<<B, 256, 0, stream>>>(fhist, cbArr, cumArr, thresh, cnts);
  k_gather<<<dim3(bpb, B), 256, 0, stream>>>(keys, thresh, cnts, cand_sort,
                                             sel_box, sel_score, A, chunks);
  k_rank<<<dim3(CAP / 256, B), 256, 0, stream>>>(cand_sort, cnts,
                                                 (const float4*)anchors,
                                                 (const float4*)deltas,
                                                 sel_box, sel_score, A);
  k_nmsmask<<<dim3(8, NW, B), 256, 0, stream>>>(sel_box, mask, maskT);
  k_scanout<<<B, 64, 0, stream>>>(sel_box, sel_score, mask, maskT, out);
}

// Round 16
// 247.320 us; speedup vs baseline: 1.1668x; 1.1293x over previous
//
#include <hip/hip_runtime.h>
#include <stdint.h>
#include <math.h>

// RPN proposal filtering: decode -> clip -> validity mask -> stable top-2000
// -> greedy NMS (IoU > 0.7) -> first 1000 kept -> (B, 1000, 5).
//
// R22: k_rank 2-D decomposed. R21's div-free nmsmask worked (56us kernel
// gone from top-5); profile exposed k_rank at 54us with VALUBusy 8.4%,
// Occupancy 5%: only ~9 live blocks/batch (<1/CU) each serially streaming
// ~2300 wave-uniform ds_read_b64 broadcasts. rank = sum of per-key-tile
// partial counts -> parallel in both dims:
//  - k_rankcnt (16 st x 16 kt x B): one 256-key tile in LDS (b128 2-key
//    vector reads), per-slot partial counts, coalesced rnk_partial write.
//    ~1300 live blocks = ~5/CU.
//  - k_scatter (16 x B): sum <=9 live partials/slot + old decode/write.
//    Dead-kt partials never written AND never read (scatter iterates only
//    live kts) -> no zeroing.
// rnk_partial (4MB) aliases `keys` (16.8MB, dead after k_gather).

#define IMGF 1024.0f
#define PRE_NMS 2000
#define POST_NMS 1000
#define NMS_THR 0.7f
#define MIN_SZ 16.0f
#define CAP 4096          // candidate buffer per batch
#define SEL 2048          // padded selection stride (>= PRE_NMS)
#define NW (SEL / 64)     // 32 mask words per row
#define CNT_STRIDE 32     // u32s per batch for counters (128 B -> own line)
#define KEY_NEGINF 0x007FFFFFu  // f2key(-inf)
#define MAXCHUNK 12
// fl32(x/y) > 0.7f  <=>  x >= IOU_T * y  (y > 0); exact in double.
#define IOU_T 0x1.6666668p-1

// Order-preserving float -> u32 key (all floats incl. -inf totally ordered).
__device__ __forceinline__ uint32_t f2key(float f) {
  uint32_t u = __float_as_uint(f);
  return (u & 0x80000000u) ? ~u : (u | 0x80000000u);
}
__device__ __forceinline__ float key2f(uint32_t k) {
  uint32_t u = (k & 0x80000000u) ? (k & 0x7FFFFFFFu) : ~k;
  return __uint_as_float(u);
}

__device__ __forceinline__ unsigned long long readlane_u64(unsigned long long v,
                                                           int lane) {
  unsigned int lo = __builtin_amdgcn_readlane((unsigned int)v, lane);
  unsigned int hi = __builtin_amdgcn_readlane((unsigned int)(v >> 32), lane);
  return ((unsigned long long)hi << 32) | lo;
}

// Mirrors reference _decode + clip, fp32.
__device__ __forceinline__ float4 decode_clip(float4 anc, float4 dlt) {
  float aw = anc.z - anc.x;
  float ah = anc.w - anc.y;
  float ax = anc.x + 0.5f * aw;
  float ay = anc.y + 0.5f * ah;
  float dw = fminf(dlt.z, 4.0f);
  float dh = fminf(dlt.w, 4.0f);
  float px = dlt.x * aw + ax;
  float py = dlt.y * ah + ay;
  float pw = expf(dw) * aw;
  float ph = expf(dh) * ah;
  float x1 = px - 0.5f * pw, y1 = py - 0.5f * ph;
  float x2 = px + 0.5f * pw, y2 = py + 0.5f * ph;
  x1 = fminf(fmaxf(x1, 0.0f), IMGF);
  y1 = fminf(fmaxf(y1, 0.0f), IMGF);
  x2 = fminf(fmaxf(x2, 0.0f), IMGF);
  y2 = fminf(fmaxf(y2, 0.0f), IMGF);
  return make_float4(x1, y1, x2, y2);
}

// K1: decode -> masked-score key; per-block LDS coarse hist of key>>24
// (finite keys only), ballot-match wave aggregation, one aggregated global
// flush per block. grid = (bpb, B).
__global__ void k_decode(const float4* __restrict__ anchors,
                         const float4* __restrict__ deltas,
                         const float* __restrict__ scores,
                         uint32_t* __restrict__ keys,
                         uint32_t* __restrict__ chist,
                         int A, int chunks) {
  int b = blockIdx.y;
  int t = threadIdx.x;  // 256
  int lane = t & 63;
  __shared__ uint32_t shist[256];
  shist[t] = 0;
  __syncthreads();
  int base_a = blockIdx.x * (chunks * 256);
  for (int c = 0; c < chunks; c++) {
    int a = base_a + c * 256 + t;
    bool inb = a < A;
    int ac = inb ? a : (A - 1);
    size_t i = (size_t)b * A + ac;
    float4 box = decode_clip(anchors[ac], deltas[i]);
    bool valid = (box.z - box.x >= MIN_SZ) && (box.w - box.y >= MIN_SZ);
    float ms = valid ? scores[i] : -INFINITY;
    uint32_t k = f2key(ms);
    if (inb) keys[i] = k;
    uint32_t bucket = k >> 24;
    bool fin = inb && (k != KEY_NEGINF);
    // lanes with equal bucket -> one LDS atomic by the leader
    unsigned long long match = __ballot(fin);
#pragma unroll
    for (int bit = 0; bit < 8; bit++) {
      bool hb = (bucket >> bit) & 1;
      unsigned long long bb = __ballot(hb && fin);
      match &= hb ? bb : ~bb;
    }
    if (fin && (__ffsll((long long)match) - 1 == lane))
      atomicAdd(&shist[bucket], (uint32_t)__popcll(match));
  }
  __syncthreads();
  uint32_t v = shist[t];
  if (v) atomicAdd(&chist[b * 256 + t], v);
}

// K2: pick coarse bucket cb s.t. countAbove(cb) < PRE_NMS <= countAbove(cb)+chist[cb].
__global__ void k_coarse(const uint32_t* __restrict__ chist,
                         int* __restrict__ cbArr,
                         uint32_t* __restrict__ cumArr) {
  int b = blockIdx.x;
  int t = threadIdx.x;  // 256
  __shared__ uint32_t sA[256];
  sA[t] = chist[b * 256 + t];
  for (int d = 1; d < 256; d <<= 1) {  // inclusive suffix scan
    __syncthreads();
    uint32_t v = sA[t] + ((t + d < 256) ? sA[t + d] : 0u);
    __syncthreads();
    sA[t] = v;
  }
  __syncthreads();
  if (t == 0 && sA[0] < PRE_NMS) {  // degenerate: < PRE_NMS finite entries
    cbArr[b] = -1;
    cumArr[b] = 0;
  }
  uint32_t nxt = (t < 255) ? sA[t + 1] : 0u;
  if (sA[t] >= PRE_NMS && nxt < PRE_NMS) {
    cbArr[b] = t;
    cumArr[b] = nxt;  // count strictly above coarse bucket t
  }
}

// K3: fine hist of key bits[23:16] for elements whose coarse bucket == cb[b].
__global__ void k_fine(const uint32_t* __restrict__ keys,
                       const int* __restrict__ cbArr,
                       uint32_t* __restrict__ fhist,
                       int A, int chunks) {
  int b = blockIdx.y;
  int t = threadIdx.x;  // 256
  int cb = cbArr[b];
  if (cb < 0) return;
  __shared__ uint32_t shist[256];
  shist[t] = 0;
  __syncthreads();
  int base_a = blockIdx.x * (chunks * 256);
  uint32_t cbu = (uint32_t)cb;
  for (int c = 0; c < chunks; c++) {
    int a = base_a + c * 256 + t;
    if (a >= A) break;
    uint32_t k = keys[(size_t)b * A + a];
    if ((k >> 24) == cbu && k != KEY_NEGINF)
      atomicAdd(&shist[(k >> 16) & 0xFFu], 1u);
  }
  __syncthreads();
  uint32_t v = shist[t];
  if (v) atomicAdd(&fhist[b * 256 + t], v);
}

// K4: final 16-bit threshold beta = (cb<<8)|d:
// count(key>>16 > beta) < PRE_NMS <= count(key>>16 >= beta), finite keys only.
__global__ void k_thresh(const uint32_t* __restrict__ fhist,
                         const int* __restrict__ cbArr,
                         const uint32_t* __restrict__ cumArr,
                         uint32_t* __restrict__ thresh,
                         uint32_t* __restrict__ cnts) {
  int b = blockIdx.x;
  int t = threadIdx.x;  // 256
  __shared__ uint32_t sA[256];
  if (t < 2) cnts[b * CNT_STRIDE + t] = 0;
  int cb = cbArr[b];
  if (cb < 0) {
    if (t == 0) thresh[b] = 0u;
    return;
  }
  uint32_t cumAbove = cumArr[b];
  sA[t] = fhist[b * 256 + t];
  for (int d = 1; d < 256; d <<= 1) {
    __syncthreads();
    uint32_t v = sA[t] + ((t + d < 256) ? sA[t + d] : 0u);
    __syncthreads();
    sA[t] = v;
  }
  __syncthreads();
  uint32_t nxt = (t < 255) ? sA[t + 1] : 0u;
  if (cumAbove + sA[t] >= PRE_NMS && cumAbove + nxt < PRE_NMS)
    thresh[b] = (uint32_t)((cb << 8) | t);
}

// K5: gather candidate KEYS ONLY (8B each), block-aggregated atomics: one
// atomicAdd per category per block. Strictly-above fills [0, c1); ties fill
// from CAP-1 downward; overflow ties dropped (only above 2096 ties/batch).
// First SEL/256 blocks per batch also default-fill sel_box/sel_score.
__global__ void k_gather(const uint32_t* __restrict__ keys,
                         const uint32_t* __restrict__ thresh,
                         uint32_t* __restrict__ cnts,
                         unsigned long long* __restrict__ cand_sort,
                         float4* __restrict__ sel_box,
                         float* __restrict__ sel_score,
                         int A, int chunks) {
  int b = blockIdx.y;
  int t = threadIdx.x;  // 256
  int lane = t & 63;
  int w = t >> 6;  // wave 0..3
  if (blockIdx.x < SEL / 256) {  // folded k_fillsel
    int r = blockIdx.x * 256 + t;
    sel_score[(size_t)b * SEL + r] = -INFINITY;
    sel_box[(size_t)b * SEL + r] = make_float4(0.0f, 0.0f, 0.0f, 0.0f);
  }
  __shared__ unsigned long long s_mA[MAXCHUNK * 4], s_mT[MAXCHUNK * 4];
  __shared__ uint32_t s_offA[MAXCHUNK * 4], s_offT[MAXCHUNK * 4];
  __shared__ uint32_t s_cA[MAXCHUNK * 4], s_cT[MAXCHUNK * 4];
  __shared__ uint32_t s_baseA, s_baseT;
  uint32_t beta = thresh[b];
  uint32_t kreg[MAXCHUNK];
  int base_a = blockIdx.x * (chunks * 256);
  for (int c = 0; c < chunks; c++) {
    int a = base_a + c * 256 + t;
    bool inb = a < A;
    uint32_t k = inb ? keys[(size_t)b * A + a] : KEY_NEGINF;
    kreg[c] = k;
    uint32_t bk = k >> 16;
    bool fin = (k != KEY_NEGINF);
    unsigned long long mA = __ballot(fin && (bk > beta));
    unsigned long long mT = __ballot(fin && (bk == beta));
    if (lane == 0) {
      s_mA[c * 4 + w] = mA;
      s_mT[c * 4 + w] = mT;
    }
  }
  __syncthreads();
  if (t < chunks * 4) {
    s_cA[t] = (uint32_t)__popcll(s_mA[t]);
    s_cT[t] = (uint32_t)__popcll(s_mT[t]);
  }
  __syncthreads();
  if (t == 0) {  // serial scan over <=44 entries, then ONE atomic per category
    uint32_t accA = 0, accT = 0;
    for (int id = 0; id < chunks * 4; id++) {
      s_offA[id] = accA;
      accA += s_cA[id];
      s_offT[id] = accT;
      accT += s_cT[id];
    }
    s_baseA = accA ? atomicAdd(&cnts[b * CNT_STRIDE + 0], accA) : 0u;
    s_baseT = accT ? atomicAdd(&cnts[b * CNT_STRIDE + 1], accT) : 0u;
  }
  __syncthreads();
  uint32_t baseA = s_baseA, baseT = s_baseT;
  unsigned long long lower = ((unsigned long long)1 << lane) - 1;
  for (int c = 0; c < chunks; c++) {
    int id = c * 4 + w;
    unsigned long long mA = s_mA[id], mT = s_mT[id];
    bool above = (mA >> lane) & 1;
    bool tie = (mT >> lane) & 1;
    if (!(above || tie)) continue;
    int pos;
    if (above) {
      pos = (int)(baseA + s_offA[id] + (uint32_t)__popcll(mA & lower));
      if (pos >= PRE_NMS) continue;  // defensive; cannot happen
    } else {
      pos = CAP - 1 - (int)(baseT + s_offT[id] + (uint32_t)__popcll(mT & lower));
      if (pos < PRE_NMS) continue;  // drop overflow ties
    }
    int a = base_a + c * 256 + t;
    // sort key: (score_key desc, anchor index asc) via descending u64 order
    cand_sort[(size_t)b * CAP + pos] =
        ((unsigned long long)kreg[c] << 32) | (uint32_t)(~(uint32_t)a);
  }
}

// K6a (R22): partial rank counts. Keys strictly distinct -> rank = #{keys >
// mine}. Block (st, kt, b): key tile kt staged in LDS (b128 2-key reads),
// each thread counts its slot (st*256+t) against the 256 tile keys, writes
// rnk_partial[b][kt][slot] (coalesced). Dead st/kt tiles exit pre-barrier
// (uniform); their partials are never read (k_scatter sums live kts only).
__global__ void k_rankcnt(const unsigned long long* __restrict__ cand_sort,
                          const uint32_t* __restrict__ cnts,
                          uint32_t* __restrict__ rnk_partial) {
  int st = blockIdx.x;  // slot tile
  int kt = blockIdx.y;  // key tile
  int b = blockIdx.z;
  int t = threadIdx.x;  // 256
  uint32_t c1 = cnts[b * CNT_STRIDE + 0];
  if (c1 > PRE_NMS) c1 = PRE_NMS;
  uint32_t c2 = cnts[b * CNT_STRIDE + 1];
  if (c2 > CAP - PRE_NMS) c2 = CAP - PRE_NMS;
  int loTie = CAP - (int)c2;
  int bs = st * 256, ks = kt * 256;
  if (bs >= (int)c1 && bs + 256 <= loTie) return;  // dead slot tile
  if (ks >= (int)c1 && ks + 256 <= loTie) return;  // dead key tile
  int s = bs + t;
  bool live = (s < (int)c1) || (s >= loTie);
  unsigned long long myKey = live ? cand_sort[(size_t)b * CAP + s] : 0ull;
  __shared__ __attribute__((aligned(16))) unsigned long long tile[256];
  int idx = ks + t;
  bool lv = (idx < (int)c1) || (idx >= loTie);
  tile[t] = lv ? cand_sort[(size_t)b * CAP + idx] : 0ull;
  __syncthreads();
  const ulonglong2* tile2 = (const ulonglong2*)tile;
  int cnt = 0;
#pragma unroll 8
  for (int j = 0; j < 128; j++) {  // ds_read_b128: 2 keys per LDS op
    ulonglong2 v = tile2[j];
    cnt += (v.x > myKey) ? 1 : 0;
    cnt += (v.y > myKey) ? 1 : 0;
  }
  rnk_partial[((size_t)b * 16 + kt) * CAP + s] = (uint32_t)cnt;  // coalesced
}

// K6b (R22): sum live-kt partials -> exact rank; decode box from embedded
// anchor index and write sel arrays (old k_rank tail). grid (16, B).
__global__ void k_scatter(const unsigned long long* __restrict__ cand_sort,
                          const uint32_t* __restrict__ rnk_partial,
                          const uint32_t* __restrict__ cnts,
                          const float4* __restrict__ anchors,
                          const float4* __restrict__ deltas,
                          float4* __restrict__ sel_box,
                          float* __restrict__ sel_score, int A) {
  int st = blockIdx.x;
  int b = blockIdx.y;
  int t = threadIdx.x;  // 256
  uint32_t c1 = cnts[b * CNT_STRIDE + 0];
  if (c1 > PRE_NMS) c1 = PRE_NMS;
  uint32_t c2 = cnts[b * CNT_STRIDE + 1];
  if (c2 > CAP - PRE_NMS) c2 = CAP - PRE_NMS;
  int loTie = CAP - (int)c2;
  int bs = st * 256;
  if (bs >= (int)c1 && bs + 256 <= loTie) return;  // dead slot tile
  int s = bs + t;
  bool live = (s < (int)c1) || (s >= loTie);
  if (!live) return;  // no barriers below; divergence fine
  int rank = 0;
  for (int kt = 0; kt < 16; kt++) {  // uniform loop; skip dead key tiles
    int ks = kt * 256;
    if (ks >= (int)c1 && ks + 256 <= loTie) continue;
    rank += (int)rnk_partial[((size_t)b * 16 + kt) * CAP + s];
  }
  if (rank < SEL) {
    unsigned long long myKey = cand_sort[(size_t)b * CAP + s];
    uint32_t a = ~((uint32_t)myKey);
    float4 box = decode_clip(anchors[a], deltas[(size_t)b * A + a]);
    sel_score[(size_t)b * SEL + rank] = key2f((uint32_t)(myKey >> 32));
    sel_box[(size_t)b * SEL + rank] = box;
  }
}

// K7: suppression bitmask, COLUMN-TILE-MAJOR output mask[b][jb][i].
// Grid (8, NW, B), 256 threads = 4 waves; block (qb, ib) covers col-tile
// quad jb = qb*4 + w, one tile per wave. IoU decision uses the EXACT
// division-free comparison (R21):
//   fl32(inter/denom) > 0.7f  <=>  (double)inter >= IOU_T*(double)denom.
__global__ void __launch_bounds__(256)
k_nmsmask(const float4* __restrict__ sel_box,
          unsigned long long* __restrict__ mask,
          unsigned long long* __restrict__ maskT) {
  int qb = blockIdx.x;  // col-tile quad 0..7
  int ib = blockIdx.y;  // row block
  if (qb * 4 + 3 < ib) return;  // whole quad below diagonal (uniform, pre-barrier)
  int b = blockIdx.z;
  int t = threadIdx.x;  // 256 = 4 waves
  int lane = t & 63;
  int w = t >> 6;
  int jb = qb * 4 + w;  // this wave's col tile (<= 31 always)
  __shared__ float4 rowb[64];
  __shared__ float rowarea[64];
  __shared__ float4 colb[4][64];
  __shared__ float colarea[4][64];
  if (t < 64) {
    float4 rb = sel_box[(size_t)b * SEL + ib * 64 + t];
    rowb[t] = rb;
    rowarea[t] = (rb.z - rb.x) * (rb.w - rb.y);
  }
  bool wvalid = (jb >= ib);
  if (wvalid) {
    float4 cbx = sel_box[(size_t)b * SEL + jb * 64 + lane];
    colb[w][lane] = cbx;
    colarea[w][lane] = (cbx.z - cbx.x) * (cbx.w - cbx.y);
  }
  __syncthreads();  // all 4 waves arrive; no barriers after this point
  if (!wvalid) return;
  float4 a = rowb[lane];
  float area_a = rowarea[lane];
  int i = ib * 64 + lane;
  unsigned long long bits = 0ull;
  if (i < PRE_NMS) {  // pad rows write zeros (never consumed anyway)
    bool diag = (jb == ib);
    int jmax = min(64, PRE_NMS - jb * 64);
    for (int jj = 0; jj < jmax; jj++) {
      if (diag && jj <= lane) continue;
      float4 bb = colb[w][jj];        // LDS broadcast
      float area_b = colarea[w][jj];  // precomputed
      float ltx = fmaxf(a.x, bb.x), lty = fmaxf(a.y, bb.y);
      float rbx = fminf(a.z, bb.z), rby = fminf(a.w, bb.w);
      float ww = fmaxf(rbx - ltx, 0.0f), hh = fmaxf(rby - lty, 0.0f);
      float inter = ww * hh;
      float denom = area_a + area_b - inter + 1e-6f;
      // denom > 0 structurally (clip keeps x1<=x2 -> areas >= 0, +1e-6).
      // Exact replacement for fl32(inter/denom) > 0.7f:
      if ((double)inter >= IOU_T * (double)denom) bits |= (1ull << jj);
    }
  }
  mask[((size_t)b * NW + jb) * SEL + i] = bits;  // coalesced 512B per wave
  if (jb == ib) {  // transpose the 64x64 diagonal block via ballots
    unsigned long long myT = 0ull;
#pragma unroll 1
    for (int jj = 0; jj < 64; jj++) {
      unsigned long long colw = __ballot((bits >> jj) & 1ull);
      if (lane == jj) myT = colw;
    }
    maskT[(size_t)b * SEL + i] = myT;
  }
}

// K8: one wave per batch. Per 64-row chunk: greedy NMS = grounded extension
// of the acyclic in-chunk attack DAG, computed by Jacobi iteration
//   K <- ballot(alive && (colm & K)==0)
// (unique fixpoint; converges in <= chain depth rounds, each ~1 ballot).
// Cross-chunk `removed` accumulates from a DOUBLE-BUFFERED LDS-DMA tile.
// Mask is column-tile-major; DMA op k fetches two 512B column segments
// (jb = 2k + lane>>5) into LDS tile [jb][row]. Accumulate: lane tw reads
// rows in staggered order jr=(j+tw)&63 with branchless per-lane bit masks;
// words tw < chunk are structurally zero (unwritten lower triangle) and
// masked out via wv.
__global__ void __launch_bounds__(64, 1)
k_scanout(const float4* __restrict__ sel_box,
          const float* __restrict__ sel_score,
          const unsigned long long* __restrict__ mask,
          const unsigned long long* __restrict__ maskT,
          float* __restrict__ out) {
  int b = blockIdx.x;
  int t = threadIdx.x;  // 64 = 1 wave
  int tw = t & 31;
  __shared__ uint32_t keptList[POST_NMS + 64];     // overshoot space
  __shared__ unsigned long long tile[2][64 * NW];  // [buf][jb*64 + row]
  unsigned long long removed = 0ull;  // lane w<32 owns word w (dup in w+32)
  int kc = 0;
  const unsigned long long* mb = mask + (size_t)b * NW * SEL;  // col-major
  const unsigned long long* tbase = maskT + (size_t)b * SEL;
  const int lastChunk = (PRE_NMS - 1) / 64;  // 31
  int cjb = t >> 5;        // column parity within a DMA op
  int ro = (t & 31) * 2;   // row offset (2 rows = 16B per lane)

  // prologue: DMA chunk 0 -> tile[0]; load chunk 0's colm + score
  {
#pragma unroll
    for (int k = 0; k < 16; k++) {
      const unsigned long long* gp =
          mb + ((size_t)(2 * k + cjb)) * SEL + ro;
      __builtin_amdgcn_global_load_lds(
          (const __attribute__((address_space(1))) uint32_t*)gp,
          (__attribute__((address_space(3))) uint32_t*)&tile[0][k * 128],
          16, 0, 0);
    }
  }
  unsigned long long colm = tbase[t];
  uint32_t scb = __float_as_uint(sel_score[(size_t)b * SEL + t]);

  for (int chunk = 0; chunk <= lastChunk; chunk++) {
    int cur = chunk & 1;
    // issue DMA for chunk+1 into the other buffer + prefetch its colm/score
    unsigned long long colm_n = 0ull;
    uint32_t scb_n = 0xFF800000u;
    if (chunk < lastChunk) {
#pragma unroll
      for (int k = 0; k < 16; k++) {
        const unsigned long long* gp =
            mb + ((size_t)(2 * k + cjb)) * SEL + (size_t)(chunk + 1) * 64 + ro;
        __builtin_amdgcn_global_load_lds(
            (const __attribute__((address_space(1))) uint32_t*)gp,
            (__attribute__((address_space(3))) uint32_t*)
                &tile[cur ^ 1][k * 128],
            16, 0, 0);
      }
      colm_n = tbase[(chunk + 1) * 64 + t];
      scb_n =
          __float_as_uint(sel_score[(size_t)b * SEL + (chunk + 1) * 64 + t]);
    }
    int rmax = PRE_NMS - chunk * 64;
    if (rmax > 64) rmax = 64;
    unsigned long long vb = __ballot(scb != 0xFF800000u);
    unsigned long long curw = readlane_u64(removed, chunk);
    unsigned long long range = (rmax >= 64) ? ~0ull : ((1ull << rmax) - 1ull);
    unsigned long long alive0 = ~curw & range;
    // Jacobi fixpoint: K_{n+1}[j] = alive0[j] && (colm[j] & K_n)==0.
    unsigned long long K = alive0;
    bool aliveb = (alive0 >> t) & 1ull;
#pragma unroll 1
    for (int it = 0; it < 64; ++it) {
      bool deadb = (colm & K) != 0ull;
      unsigned long long Kn = __ballot(aliveb && !deadb);
      if (Kn == K) break;
      K = Kn;
    }
    unsigned long long keptbits = K;
    // bookkeeping: lane-parallel keptList append via popcount rank
    unsigned long long kv = keptbits & vb;
    if ((kv >> t) & 1ull) {
      int rank = (int)__popcll(kv & ((1ull << t) - 1ull));
      keptList[kc + rank] = (uint32_t)(chunk * 64 + t);
    }
    kc += (int)__popcll(kv);
    if (kc >= POST_NMS) break;      // future chunks irrelevant
    if (chunk == lastChunk) break;  // no future chunks
    // Drain this chunk's tile DMA (issued LAST iteration; fully overlapped).
    // Newest 18 VMEM ops (this iteration's 16 DMA + colm_n + scb_n) may
    // remain outstanding.
    asm volatile("s_waitcnt vmcnt(18)" ::: "memory");
    __builtin_amdgcn_sched_barrier(0);
    // accumulate removed: lane tw owns word tw = column tw; read rows in
    // staggered order jr=(j+tw)&63, branchless bit masks.
    unsigned long long acc = 0ull;
#pragma unroll
    for (int j = 0; j < 64; j++) {
      int jr = (j + tw) & 63;
      unsigned long long v = tile[cur][tw * 64 + jr];
      unsigned long long mk =
          (unsigned long long)(-(long long)((keptbits >> jr) & 1ull));
      acc |= v & mk;
    }
    // words tw < chunk are structurally zero (unwritten lower triangle)
    unsigned long long wv = (tw >= chunk) ? ~0ull : 0ull;
    removed |= acc & wv;
    // keep next iteration's DMA (overwrites tile[cur]) below these ds_reads
    __builtin_amdgcn_sched_barrier(0);
    colm = colm_n;
    scb = scb_n;
  }
  int kcc = kc < POST_NMS ? kc : POST_NMS;
  __syncthreads();
  for (int r = t; r < POST_NMS; r += 64) {
    float4 bx = make_float4(0.0f, 0.0f, 0.0f, 0.0f);
    float sc = 0.0f;
    if (r < kcc) {
      int i = (int)keptList[r];
      bx = sel_box[(size_t)b * SEL + i];
      sc = sel_score[(size_t)b * SEL + i];
    }
    float* o = out + ((size_t)b * POST_NMS + r) * 5;
    o[0] = bx.x;
    o[1] = bx.y;
    o[2] = bx.z;
    o[3] = bx.w;
    o[4] = sc;
  }
}

extern "C" void kernel_launch(void* const* d_in, const int* in_sizes, int n_in,
                              void* d_out, int out_size, void* d_ws, size_t ws_size,
                              hipStream_t stream) {
  const float* anchors = (const float*)d_in[0];  // (A, 4)
  const float* deltas = (const float*)d_in[1];   // (B, A, 4)
  const float* scores = (const float*)d_in[2];   // (B, A)
  int A = in_sizes[0] / 4;
  int BA = in_sizes[2];
  int B = BA / A;
  float* out = (float*)d_out;

  char* ws = (char*)d_ws;
  size_t off = 0;
  uint32_t* keys = (uint32_t*)(ws + off);
  off += (size_t)BA * 4;
  uint32_t* chist = (uint32_t*)(ws + off);
  off += (size_t)B * 256 * 4;
  uint32_t* fhist = (uint32_t*)(ws + off);
  off += (size_t)B * 256 * 4;
  int* cbArr = (int*)(ws + off);
  off += (size_t)B * 4;
  uint32_t* cumArr = (uint32_t*)(ws + off);
  off += (size_t)B * 4;
  uint32_t* thresh = (uint32_t*)(ws + off);
  off += (size_t)B * 4;
  off = (off + 127) & ~(size_t)127;
  uint32_t* cnts = (uint32_t*)(ws + off);
  off += (size_t)B * CNT_STRIDE * 4;
  off = (off + 15) & ~(size_t)15;
  unsigned long long* cand_sort = (unsigned long long*)(ws + off);
  off += (size_t)B * CAP * 8;
  float4* sel_box = (float4*)(ws + off);
  off += (size_t)B * SEL * 16;
  float* sel_score = (float*)(ws + off);
  off += (size_t)B * SEL * 4;
  unsigned long long* mask = (unsigned long long*)(ws + off);
  off += (size_t)B * NW * SEL * 8;  // column-tile-major [B][NW][SEL]
  unsigned long long* maskT = (unsigned long long*)(ws + off);
  off += (size_t)B * SEL * 8;  // 256 KB
  // rnk_partial (B*16*CAP u32 = 4 MB) ALIASES keys (16.8 MB): keys is dead
  // after k_gather, and k_rankcnt/k_scatter run strictly after it.
  uint32_t* rnk_partial = keys;
  // total ~27.3 MB

  // Block geometry for per-batch streaming kernels: A = 261888 = 256*11*93.
  int chunks = (A % (256 * 11) == 0) ? 11 : 1;
  int bpb = (A + 256 * chunks - 1) / (256 * chunks);  // blocks per batch

  hipMemsetAsync(chist, 0, (size_t)B * 256 * 4 * 2, stream);  // chist+fhist
  k_decode<<<dim3(bpb, B), 256, 0, stream>>>((const float4*)anchors,
                                             (const float4*)deltas, scores,
                                             keys, chist, A, chunks);
  k_coarse<<<B, 256, 0, stream>>>(chist, cbArr, cumArr);
  k_fine<<<dim3(bpb, B), 256, 0, stream>>>(keys, cbArr, fhist, A, chunks);
  k_thresh<<<B, 256, 0, stream>>>(fhist, cbArr, cumArr, thresh, cnts);
  k_gather<<<dim3(bpb, B), 256, 0, stream>>>(keys, thresh, cnts, cand_sort,
                                             sel_box, sel_score, A, chunks);
  k_rankcnt<<<dim3(CAP / 256, CAP / 256, B), 256, 0, stream>>>(cand_sort, cnts,
                                                               rnk_partial);
  k_scatter<<<dim3(CAP / 256, B), 256, 0, stream>>>(cand_sort, rnk_partial,
                                                    cnts, (const float4*)anchors,
                                                    (const float4*)deltas,
                                                    sel_box, sel_score, A);
  k_nmsmask<<<dim3(8, NW, B), 256, 0, stream>>>(sel_box, mask, maskT);
  k_scanout<<<B, 64, 0, stream>>>(sel_box, sel_score, mask, maskT, out);
}